// Round 12
// baseline (507.203 us; speedup 1.0000x reference)
//
#include <hip/hip_runtime.h>
#include <math.h>

#define L 4096
#define DM 512
#define DI 1024
#define DS 16
#define RNK 32
#define BD 64   // d-columns per scan block

typedef unsigned short u16;
typedef __attribute__((ext_vector_type(8))) short bfv8;   // 8 bf16 (4 VGPRs)
typedef __attribute__((ext_vector_type(4))) float f32x4;

__device__ __forceinline__ u16 f2bf(float f) {
  unsigned int u = __float_as_uint(f);
  u = (u + 0x7fff + ((u >> 16) & 1)) >> 16;   // round-to-nearest-even
  return (u16)u;
}
__device__ __forceinline__ float bf2f(u16 h) {
  return __uint_as_float(((unsigned int)h) << 16);
}

__device__ __forceinline__ void gload16(const void* g, void* l) {
  __builtin_amdgcn_global_load_lds(
      (const __attribute__((address_space(1))) void*)g,
      (__attribute__((address_space(3))) void*)l, 16, 0, 0);
}

// ---------------------------------------------------------------------------
// split fp32 -> (hi, lo) bf16 planes. n4 = n/4.
// ---------------------------------------------------------------------------
__global__ __launch_bounds__(256) void split_bf(
    const float* __restrict__ in, u16* __restrict__ hi, u16* __restrict__ lo,
    int n4) {
  int i = blockIdx.x * 256 + threadIdx.x;
  if (i >= n4) return;
  float4 v = ((const float4*)in)[i];
  ushort4 h4, l4;
  h4.x = f2bf(v.x); l4.x = f2bf(v.x - bf2f(h4.x));
  h4.y = f2bf(v.y); l4.y = f2bf(v.y - bf2f(h4.y));
  h4.z = f2bf(v.z); l4.z = f2bf(v.z - bf2f(h4.z));
  h4.w = f2bf(v.w); l4.w = f2bf(v.w - bf2f(h4.w));
  ((ushort4*)hi)[i] = h4;
  ((ushort4*)lo)[i] = l4;
}

// ---------------------------------------------------------------------------
// Split-bf16 MFMA GEMM:  C = A @ W^T.  PARTIAL: grid.z K-slices write raw
// fp32 partials at Cf + kz*M*N (epilogue deferred to kreduce).
// ---------------------------------------------------------------------------
template <int BN_, int WM, int WN, int ACT, int BIAS, int RES, int OSPLIT,
          int PARTIAL = 0>
__global__ __launch_bounds__(256) void gemm_mfma(
    const u16* __restrict__ Ah, const u16* __restrict__ Al,
    const u16* __restrict__ Wh, const u16* __restrict__ Wl,
    const float* __restrict__ bias, const float* __restrict__ res,
    float* __restrict__ Cf, u16* __restrict__ Ch, u16* __restrict__ Cl,
    int M, int N, int K) {
  constexpr int BM_ = 128, BK_ = 32;
  constexpr int MSUB = BM_ / WM, NSUB = BN_ / WN;
  constexpr int MR = MSUB / 16, NR = NSUB / 16;
  __shared__ u16 smem[2 * BM_ * BK_ + 2 * BN_ * BK_];
  u16* sAh = smem;
  u16* sAl = smem + BM_ * BK_;
  u16* sBh = smem + 2 * BM_ * BK_;
  u16* sBl = sBh + BN_ * BK_;
  const int lane = threadIdx.x & 63, wid = threadIdx.x >> 6;
  const int wrow = wid / WN, wcol = wid % WN;
  const int bm = blockIdx.y * BM_, bn = blockIdx.x * BN_;
  const int fr = lane & 15, kq = lane >> 4;
  const int kz = blockIdx.z;
  const int kslice = K / gridDim.z;
  const int kbeg = kz * kslice, kend = kbeg + kslice;

  f32x4 acc[MR][NR];
#pragma unroll
  for (int m = 0; m < MR; ++m)
#pragma unroll
    for (int n = 0; n < NR; ++n) acc[m][n] = (f32x4){0.f, 0.f, 0.f, 0.f};

  for (int kt = kbeg; kt < kend; kt += BK_) {
#pragma unroll
    for (int s = wid; s < BM_ / 16; s += 4) {
      int chunk = s * 64 + lane;
      int row = chunk >> 2, c4 = chunk & 3;
      size_t go = (size_t)(bm + row) * K + kt + c4 * 8;
      gload16(Ah + go, sAh + s * 512);
      gload16(Al + go, sAl + s * 512);
    }
#pragma unroll
    for (int s = wid; s < BN_ / 16; s += 4) {
      int chunk = s * 64 + lane;
      int row = chunk >> 2, c4 = chunk & 3;
      size_t go = (size_t)(bn + row) * K + kt + c4 * 8;
      gload16(Wh + go, sBh + s * 512);
      gload16(Wl + go, sBl + s * 512);
    }
    __syncthreads();

    bfv8 ah[MR], al[MR], bh[NR], bl[NR];
#pragma unroll
    for (int m = 0; m < MR; ++m) {
      int row = wrow * MSUB + m * 16 + fr;
      ah[m] = *(const bfv8*)(sAh + row * 32 + kq * 8);
      al[m] = *(const bfv8*)(sAl + row * 32 + kq * 8);
    }
#pragma unroll
    for (int n = 0; n < NR; ++n) {
      int row = wcol * NSUB + n * 16 + fr;
      bh[n] = *(const bfv8*)(sBh + row * 32 + kq * 8);
      bl[n] = *(const bfv8*)(sBl + row * 32 + kq * 8);
    }
#pragma unroll
    for (int m = 0; m < MR; ++m)
#pragma unroll
      for (int n = 0; n < NR; ++n) {
        acc[m][n] = __builtin_amdgcn_mfma_f32_16x16x32_bf16(ah[m], bh[n], acc[m][n], 0, 0, 0);
        acc[m][n] = __builtin_amdgcn_mfma_f32_16x16x32_bf16(ah[m], bl[n], acc[m][n], 0, 0, 0);
        acc[m][n] = __builtin_amdgcn_mfma_f32_16x16x32_bf16(al[m], bh[n], acc[m][n], 0, 0, 0);
      }
    __syncthreads();
  }

#pragma unroll
  for (int m = 0; m < MR; ++m)
#pragma unroll
    for (int n = 0; n < NR; ++n) {
      int col = bn + wcol * NSUB + n * 16 + fr;
      float bv = 0.f;
      if (BIAS) bv = bias[col];
#pragma unroll
      for (int j = 0; j < 4; ++j) {
        int row = bm + wrow * MSUB + m * 16 + kq * 4 + j;
        if (PARTIAL) {
          Cf[(size_t)kz * M * N + (size_t)row * N + col] = acc[m][n][j];
          continue;
        }
        float v = acc[m][n][j] + bv;
        if (ACT == 1) v = fmaxf(v, 0.f);
        if (ACT == 2) v = tanhf(v);
        if (RES) v += res[(size_t)row * N + col];
        if (OSPLIT) {
          u16 hv = f2bf(v);
          Ch[(size_t)row * N + col] = hv;
          Cl[(size_t)row * N + col] = f2bf(v - bf2f(hv));
        } else {
          Cf[(size_t)row * N + col] = v;
        }
      }
    }
}

// ---------------------------------------------------------------------------
// kreduce: sum KS fp32 partials + epilogue. i indexes float4; N % 4 == 0.
// ---------------------------------------------------------------------------
template <int KS, int ACT, int BIAS, int RES>
__global__ __launch_bounds__(256) void kreduce(
    const float* __restrict__ part, const float* __restrict__ bias,
    const float* __restrict__ res, float* __restrict__ Cf, int MN, int N) {
  int i = blockIdx.x * 256 + threadIdx.x;
  if (i * 4 >= MN) return;
  const float4* p4 = (const float4*)part;
  float4 s = p4[i];
#pragma unroll
  for (int k = 1; k < KS; ++k) {
    float4 v = p4[i + (size_t)k * (MN / 4)];
    s.x += v.x; s.y += v.y; s.z += v.z; s.w += v.w;
  }
  if (BIAS) {
    int col = (i * 4) % N;
    float4 b = *(const float4*)(bias + col);
    s.x += b.x; s.y += b.y; s.z += b.z; s.w += b.w;
  }
  if (ACT == 1) {
    s.x = fmaxf(s.x, 0.f); s.y = fmaxf(s.y, 0.f);
    s.z = fmaxf(s.z, 0.f); s.w = fmaxf(s.w, 0.f);
  }
  if (ACT == 2) {
    s.x = tanhf(s.x); s.y = tanhf(s.y); s.z = tanhf(s.z); s.w = tanhf(s.w);
  }
  if (RES) {
    float4 r = ((const float4*)res)[i];
    s.x += r.x; s.y += r.y; s.z += r.z; s.w += r.w;
  }
  ((float4*)Cf)[i] = s;
}

// ---------------------------------------------------------------------------
// LayerNorm rows of (L,512); writes bf16 hi/lo planes (+fp32 if F32OUT).
// ---------------------------------------------------------------------------
template <int F32OUT>
__global__ __launch_bounds__(64) void ln_kernel(
    const float* __restrict__ x, const float* __restrict__ w,
    const float* __restrict__ b, float* __restrict__ of,
    u16* __restrict__ oh, u16* __restrict__ ol) {
  const int l = blockIdx.x, t = threadIdx.x;
  const float* row = x + (size_t)l * DM;
  float4 v0 = *(const float4*)(row + t * 8);
  float4 v1 = *(const float4*)(row + t * 8 + 4);
  float vals[8] = {v0.x, v0.y, v0.z, v0.w, v1.x, v1.y, v1.z, v1.w};
  float s = 0.f;
#pragma unroll
  for (int i = 0; i < 8; ++i) s += vals[i];
#pragma unroll
  for (int off = 1; off < 64; off <<= 1) s += __shfl_xor(s, off);
  float m = s * (1.f / DM);
  float q = 0.f;
#pragma unroll
  for (int i = 0; i < 8; ++i) { float dd = vals[i] - m; q += dd * dd; }
#pragma unroll
  for (int off = 1; off < 64; off <<= 1) q += __shfl_xor(q, off);
  float rs = 1.f / sqrtf(q * (1.f / DM) + 1e-5f);
  float4 w0 = *(const float4*)(w + t * 8);
  float4 w1 = *(const float4*)(w + t * 8 + 4);
  float4 b0 = *(const float4*)(b + t * 8);
  float4 b1 = *(const float4*)(b + t * 8 + 4);
  float wv[8] = {w0.x, w0.y, w0.z, w0.w, w1.x, w1.y, w1.z, w1.w};
  float bb[8] = {b0.x, b0.y, b0.z, b0.w, b1.x, b1.y, b1.z, b1.w};
  ushort4 h4[2], l4[2];
#pragma unroll
  for (int i = 0; i < 8; ++i) {
    float o = (vals[i] - m) * rs * wv[i] + bb[i];
    u16 hv = f2bf(o);
    ((u16*)h4)[i] = hv;
    ((u16*)l4)[i] = f2bf(o - bf2f(hv));
    vals[i] = o;
  }
  size_t base = (size_t)l * DM + t * 8;
  *(ushort4*)(oh + base) = h4[0];
  *(ushort4*)(oh + base + 4) = h4[1];
  *(ushort4*)(ol + base) = l4[0];
  *(ushort4*)(ol + base + 4) = l4[1];
  if (F32OUT) {
    *(float4*)(of + base) = make_float4(vals[0], vals[1], vals[2], vals[3]);
    *(float4*)(of + base + 4) = make_float4(vals[4], vals[5], vals[6], vals[7]);
  }
}

// ---------------------------------------------------------------------------
// Depthwise causal conv (k=4) + SiLU; in/out are bf16 hi/lo planes.
// ---------------------------------------------------------------------------
__global__ __launch_bounds__(256) void conv_silu(
    const u16* __restrict__ xzh, const u16* __restrict__ xzl,
    const float* __restrict__ cw, const float* __restrict__ cb,
    u16* __restrict__ xch, u16* __restrict__ xcl) {
  const int idx = blockIdx.x * 256 + threadIdx.x;
  const int l = idx >> 10, d = idx & 1023;
  float s = cb[d];
  float4 w4 = *(const float4*)(cw + d * 4);
  const float wk[4] = {w4.x, w4.y, w4.z, w4.w};
#pragma unroll
  for (int k = 0; k < 4; ++k) {
    int ll = l - 3 + k;
    if (ll >= 0) {
      size_t o = (size_t)ll * (2 * DI) + d;
      s += (bf2f(xzh[o]) + bf2f(xzl[o])) * wk[k];
    }
  }
  float v = s / (1.f + __expf(-s));
  u16 hv = f2bf(v);
  xch[idx] = hv;
  xcl[idx] = f2bf(v - bf2f(hv));
}

// ---------------------------------------------------------------------------
// dt = softplus(dbc[:, :32] @ dtw^T + dtb), tiled: block = 256 d x 32 l.
// ---------------------------------------------------------------------------
__global__ __launch_bounds__(256) void dt_fast(
    const float* __restrict__ dbc, const float* __restrict__ dtw,
    const float* __restrict__ dtb, float* __restrict__ dt) {
  __shared__ float s[32][33];
  const int t = threadIdx.x;
  const int d = blockIdx.x * 256 + t;
  const int l0 = blockIdx.y * 32;
  {
    int r = t >> 3, c4 = t & 7;
    float4 v = *(const float4*)(dbc + (size_t)(l0 + r) * 64 + c4 * 4);
    s[r][c4 * 4 + 0] = v.x; s[r][c4 * 4 + 1] = v.y;
    s[r][c4 * 4 + 2] = v.z; s[r][c4 * 4 + 3] = v.w;
  }
  __syncthreads();
  float wk[RNK];
#pragma unroll
  for (int k = 0; k < RNK; k += 4) {
    float4 w4 = *(const float4*)(dtw + (size_t)d * RNK + k);
    wk[k] = w4.x; wk[k + 1] = w4.y; wk[k + 2] = w4.z; wk[k + 3] = w4.w;
  }
  const float bias = dtb[d];
  for (int l = 0; l < 32; ++l) {
    float acc = bias;
#pragma unroll
    for (int k = 0; k < RNK; ++k) acc += s[l][k] * wk[k];
    float sp = fmaxf(acc, 0.f) + __logf(1.f + __expf(-fabsf(acc)));
    dt[(size_t)(l0 + l) * DI + d] = sp;
  }
}

// ---------------------------------------------------------------------------
// LDS-staged chunked scan, templated on chunk length CTP.
// Block: 64 d x CTP timesteps, 256 thr (4 subs/d, 4 states/sub).
// part1 uses P = exp(A * sum(dt)).
// ---------------------------------------------------------------------------
template <int CTP>
__global__ __launch_bounds__(256) void scan_part1(
    const u16* __restrict__ xch, const u16* __restrict__ xcl,
    const float* __restrict__ dt, const float* __restrict__ dbc,
    const float* __restrict__ A_log, float* __restrict__ Pbuf,
    float* __restrict__ Sbuf) {
  __shared__ float sdt[CTP * BD];
  __shared__ float sx[CTP * BD];
  __shared__ float sB[CTP * 16];
  const int t = threadIdx.x;
  const int d0 = blockIdx.x * BD;
  const int c = blockIdx.y;
  const int l0 = c * CTP;
#pragma unroll
  for (int it = 0; it < CTP / 4; ++it) {
    int idx = it * 256 + t;
    int l = idx >> 6, dc = idx & 63;
    size_t o = (size_t)(l0 + l) * DI + d0 + dc;
    sdt[idx] = dt[o];
    sx[idx] = bf2f(xch[o]) + bf2f(xcl[o]);
  }
#pragma unroll
  for (int it = 0; it < CTP / 16; ++it) {
    int idx = it * 256 + t;
    int l = idx >> 4, col = idx & 15;
    sB[idx] = dbc[(size_t)(l0 + l) * 64 + RNK + col];
  }
  __syncthreads();
  const int sub = t & 3;
  const int dl = t >> 2;
  const int d = d0 + dl;
  float A[4];
  {
    float4 a4 = *(const float4*)(A_log + (size_t)d * DS + sub * 4);
    A[0] = -__expf(a4.x); A[1] = -__expf(a4.y);
    A[2] = -__expf(a4.z); A[3] = -__expf(a4.w);
  }
  float S4[4] = {0.f, 0.f, 0.f, 0.f};
  float dtsum = 0.f;
  for (int l = 0; l < CTP; ++l) {
    float dtv = sdt[l * BD + dl];
    float xv = sx[l * BD + dl];
    float4 Bv = *(const float4*)(sB + l * 16 + sub * 4);
    float dx = dtv * xv;
    dtsum += dtv;
    const float B[4] = {Bv.x, Bv.y, Bv.z, Bv.w};
#pragma unroll
    for (int j = 0; j < 4; ++j) {
      float dA = __expf(dtv * A[j]);
      S4[j] = dA * S4[j] + B[j] * dx;
    }
  }
  size_t po = ((size_t)c * DI + d) * DS + sub * 4;
  *(float4*)(Pbuf + po) = make_float4(__expf(A[0] * dtsum), __expf(A[1] * dtsum),
                                      __expf(A[2] * dtsum), __expf(A[3] * dtsum));
  *(float4*)(Sbuf + po) = make_float4(S4[0], S4[1], S4[2], S4[3]);
}

// carry: sequential over chunks; overwrites S in place with Hin (pre-state).
__global__ __launch_bounds__(256) void scan_carry(
    const float* __restrict__ Pbuf, float* __restrict__ Sbuf, int nc) {
  const int p = blockIdx.x * 256 + threadIdx.x;  // 16384
  float H = 0.f;
  for (int c = 0; c < nc; ++c) {
    const size_t o = (size_t)c * (DI * DS) + p;
    float Pv = Pbuf[o], Sv = Sbuf[o];
    Sbuf[o] = H;
    H = Pv * H + Sv;
  }
}

template <int CTP>
__global__ __launch_bounds__(256) void scan_part2(
    const u16* __restrict__ xch, const u16* __restrict__ xcl,
    const float* __restrict__ dt, const float* __restrict__ dbc,
    const float* __restrict__ Hin, const u16* __restrict__ xzh,
    const u16* __restrict__ xzl, u16* __restrict__ yh, u16* __restrict__ yl,
    const float* __restrict__ A_log, const float* __restrict__ D_p) {
  __shared__ float sdt[CTP * BD];
  __shared__ float sx[CTP * BD];
  __shared__ float sB[CTP * 16];
  __shared__ float sC[CTP * 16];
  const int t = threadIdx.x;
  const int d0 = blockIdx.x * BD;
  const int c = blockIdx.y;
  const int l0 = c * CTP;
#pragma unroll
  for (int it = 0; it < CTP / 4; ++it) {
    int idx = it * 256 + t;
    int l = idx >> 6, dc = idx & 63;
    size_t o = (size_t)(l0 + l) * DI + d0 + dc;
    sdt[idx] = dt[o];
    sx[idx] = bf2f(xch[o]) + bf2f(xcl[o]);
  }
#pragma unroll
  for (int it = 0; it < CTP / 16; ++it) {
    int idx = it * 256 + t;
    int l = idx >> 4, col = idx & 15;
    size_t ro = (size_t)(l0 + l) * 64 + RNK + col;
    sB[idx] = dbc[ro];
    sC[idx] = dbc[ro + DS];
  }
  __syncthreads();
  const int sub = t & 3;
  const int dl = t >> 2;
  const int d = d0 + dl;
  float A[4], hst[4];
  {
    float4 a4 = *(const float4*)(A_log + (size_t)d * DS + sub * 4);
    A[0] = -__expf(a4.x); A[1] = -__expf(a4.y);
    A[2] = -__expf(a4.z); A[3] = -__expf(a4.w);
    float4 h4 = *(const float4*)(Hin + ((size_t)c * DI + d) * DS + sub * 4);
    hst[0] = h4.x; hst[1] = h4.y; hst[2] = h4.z; hst[3] = h4.w;
  }
  const float Dp = D_p[d];
  for (int l = 0; l < CTP; ++l) {
    float dtv = sdt[l * BD + dl];
    float xv = sx[l * BD + dl];
    float4 Bv = *(const float4*)(sB + l * 16 + sub * 4);
    float4 Cv = *(const float4*)(sC + l * 16 + sub * 4);
    float dx = dtv * xv;
    const float B[4] = {Bv.x, Bv.y, Bv.z, Bv.w};
    const float C[4] = {Cv.x, Cv.y, Cv.z, Cv.w};
    float y = 0.f;
#pragma unroll
    for (int j = 0; j < 4; ++j) {
      float dA = __expf(dtv * A[j]);
      hst[j] = dA * hst[j] + B[j] * dx;
      y += hst[j] * C[j];
    }
    y += __shfl_xor(y, 1);
    y += __shfl_xor(y, 2);
    if (sub == 0) {
      size_t o = (size_t)(l0 + l) * DI + d;
      size_t zo = (size_t)(l0 + l) * (2 * DI) + DI + d;
      float zv = bf2f(xzh[zo]) + bf2f(xzl[zo]);
      float yv = y + Dp * xv;
      float out = yv * (zv / (1.f + __expf(-zv)));
      u16 hv = f2bf(out);
      yh[o] = hv;
      yl[o] = f2bf(out - bf2f(hv));
    }
  }
}

// ---------------------------------------------------------------------------
// tail: attention pooling + logits
// ---------------------------------------------------------------------------
__global__ __launch_bounds__(64) void attn2_kernel(
    const float* __restrict__ tb, const float* __restrict__ w2,
    const float* __restrict__ b2, float* __restrict__ avec) {
  const int l = blockIdx.x, t = threadIdx.x;
  float acc = tb[(size_t)l * 128 + t] * w2[t] +
              tb[(size_t)l * 128 + 64 + t] * w2[64 + t];
#pragma unroll
  for (int off = 1; off < 64; off <<= 1) acc += __shfl_xor(acc, off);
  if (t == 0) avec[l] = acc + b2[0];
}

__global__ __launch_bounds__(256) void softmax4096(
    const float* __restrict__ a, float* __restrict__ w) {
  __shared__ float sm[4];
  const int t = threadIdx.x;
  float vals[16];
  float m = -1e30f;
#pragma unroll
  for (int i = 0; i < 16; ++i) { vals[i] = a[t + i * 256]; m = fmaxf(m, vals[i]); }
#pragma unroll
  for (int off = 1; off < 64; off <<= 1) m = fmaxf(m, __shfl_xor(m, off));
  if ((t & 63) == 0) sm[t >> 6] = m;
  __syncthreads();
  m = fmaxf(fmaxf(sm[0], sm[1]), fmaxf(sm[2], sm[3]));
  __syncthreads();
  float s = 0.f;
#pragma unroll
  for (int i = 0; i < 16; ++i) { vals[i] = expf(vals[i] - m); s += vals[i]; }
#pragma unroll
  for (int off = 1; off < 64; off <<= 1) s += __shfl_xor(s, off);
  if ((t & 63) == 0) sm[t >> 6] = s;
  __syncthreads();
  s = sm[0] + sm[1] + sm[2] + sm[3];
  float inv = 1.f / s;
#pragma unroll
  for (int i = 0; i < 16; ++i) w[t + i * 256] = vals[i] * inv;
}

__global__ __launch_bounds__(256) void pooled_partial(
    const float* __restrict__ w, const float* __restrict__ hn,
    float* __restrict__ partial) {
  const int b = blockIdx.x;
  const int t = threadIdx.x;
  float acc0 = 0.f, acc1 = 0.f;
  for (int l = b * 128; l < b * 128 + 128; ++l) {
    float wl = w[l];
    acc0 += wl * hn[(size_t)l * DM + t];
    acc1 += wl * hn[(size_t)l * DM + t + 256];
  }
  partial[b * DM + t] = acc0;
  partial[b * DM + t + 256] = acc1;
}

__global__ __launch_bounds__(256) void pooled_reduce(
    const float* __restrict__ partial, float* __restrict__ pooled) {
  const int d = blockIdx.x * 256 + threadIdx.x;
  float s = 0.f;
  for (int b = 0; b < 32; ++b) s += partial[b * DM + d];
  pooled[d] = s;
}

__global__ __launch_bounds__(128) void logits_kernel(
    const float* __restrict__ pooled, const float* __restrict__ cls_w,
    const float* __restrict__ cls_b, float* __restrict__ out) {
  const int c = threadIdx.x >> 6, lane = threadIdx.x & 63;
  float acc = 0.f;
  for (int j = lane; j < DM; j += 64) acc += pooled[j] * cls_w[c * DM + j];
#pragma unroll
  for (int off = 1; off < 64; off <<= 1) acc += __shfl_xor(acc, off);
  if (lane == 0) out[c] = acc + cls_b[c];
}

// ---------------------------------------------------------------------------
extern "C" void kernel_launch(void* const* d_in, const int* in_sizes, int n_in,
                              void* d_out, int out_size, void* d_ws,
                              size_t ws_size, hipStream_t stream) {
  const float* x        = (const float*)d_in[0];
  const float* fc1_w    = (const float*)d_in[1];
  const float* fc1_b    = (const float*)d_in[2];
  const float* ln_w     = (const float*)d_in[3];
  const float* ln_b     = (const float*)d_in[4];
  const float* in_projw = (const float*)d_in[5];
  const float* conv_w   = (const float*)d_in[6];
  const float* conv_b   = (const float*)d_in[7];
  const float* x_projw  = (const float*)d_in[8];
  const float* dt_w     = (const float*)d_in[9];
  const float* dt_b     = (const float*)d_in[10];
  const float* A_log    = (const float*)d_in[11];
  const float* D_p      = (const float*)d_in[12];
  const float* out_projw= (const float*)d_in[13];
  const float* norm_w   = (const float*)d_in[14];
  const float* norm_b   = (const float*)d_in[15];
  const float* attn_w1  = (const float*)d_in[16];
  const float* attn_b1  = (const float*)d_in[17];
  const float* attn_w2  = (const float*)d_in[18];
  const float* attn_b2  = (const float*)d_in[19];
  const float* cls_w    = (const float*)d_in[20];
  const float* cls_b    = (const float*)d_in[21];

  char* p = (char*)d_ws;
  const size_t MB = 1024 * 1024;
  float* h    = (float*)(p);             // 8MB: L*DM f32
  float* dbc  = (float*)(p + 8 * MB);    // 1MB: L*64 f32
  float* dt   = (float*)(p + 9 * MB);    // 16MB: L*DI f32
  float* tb   = dt;                      // attn1 out aliases dt
  float* gpart= dt;                      // fc1/out_proj K-split partials (16MB)
  float* Pbuf = (float*)(p + 25 * MB);   // 8MB max (NC=128)
  float* xpart= Pbuf;                    // x_proj partials (8MB, pre-scan)
  float* hn   = Pbuf;                    // f32, used only after scans done
  float* avec = (float*)(p + 33 * MB);           // 16KB
  float* wvec = avec + L;                        // 16KB
  float* part = wvec + L;                        // 64KB
  float* pool = part + 32 * DM;                  // 2KB
  u16* xzh = (u16*)(p + 34 * MB);        // 16MB: L*2DI
  u16* xzl = (u16*)(p + 50 * MB);        // 16MB
  float* apart = (float*)(p + 34 * MB);  // attn1 partials (8MB, xz dead then)
  u16* yh  = (u16*)(p + 66 * MB);        // 8MB: L*DI (hnh aliases)
  u16* yl  = (u16*)(p + 74 * MB);        // 8MB (hnl aliases)
  u16* hnh = yh;
  u16* hnl = yl;
  u16* xch = (u16*)(p + 82 * MB);        // 8MB: L*DI (xh aliases)
  u16* xcl = (u16*)(p + 90 * MB);        // 8MB (xl aliases)
  u16* xh = xch;
  u16* xl = xcl;
  u16* wfh = (u16*)(p + 98 * MB);        // 1MB: fc1_w 512*1024
  u16* wfl = wfh + 524288;               // 1MB
  u16* wih = (u16*)(p + 100 * MB);       // 4MB: in_proj 2*2048*512
  u16* wil = (u16*)(p + 104 * MB);       // 4MB
  u16* wxh = (u16*)(p + 108 * MB);       // .25MB: x_proj 2*64*1024
  u16* wxl = wxh + 131072;
  u16* woh = (u16*)(p + 109 * MB);       // 2MB: out_proj 2*512*1024
  u16* wol = (u16*)(p + 111 * MB);       // 2MB
  u16* wah = (u16*)(p + 113 * MB);       // .125MB: attn_w1 128*512
  u16* wal = wah + 65536;

  // Scan chunking: NC=128/CT=32 (8 blocks/CU) when workspace allows
  // (Sbuf 8MB at [114,122) — R9 empirically proved ws >= 123MB);
  // else proven NC=64 map (Pbuf [25,29), Sbuf [29,33)).
  const bool big = ws_size >= (size_t)122 * MB;
  const int nc = big ? 128 : 64;
  float* Sbuf = big ? (float*)(p + 114 * MB) : (float*)(p + 29 * MB);

  // ---- split inputs/weights to bf16 hi/lo planes ----
  split_bf<<<4096, 256, 0, stream>>>(x, xh, xl, L * DI / 4);
  split_bf<<<512, 256, 0, stream>>>(fc1_w, wfh, wfl, 524288 / 4);
  split_bf<<<2048, 256, 0, stream>>>(in_projw, wih, wil, 2097152 / 4);
  split_bf<<<128, 256, 0, stream>>>(x_projw, wxh, wxl, 131072 / 4);
  split_bf<<<1024, 256, 0, stream>>>(out_projw, woh, wol, 1048576 / 4);
  split_bf<<<64, 256, 0, stream>>>(attn_w1, wah, wal, 65536 / 4);

  // fc1: h = relu(x @ fc1_w^T + b)  K=1024 split 2; partial in gpart
  gemm_mfma<128, 2, 2, 0, 0, 0, 0, 1><<<dim3(4, 32, 2), 256, 0, stream>>>(
      xh, xl, wfh, wfl, nullptr, nullptr, gpart, nullptr, nullptr,
      L, DM, 1024);
  kreduce<2, 1, 1, 0><<<2048, 256, 0, stream>>>(
      gpart, fc1_b, nullptr, h, L * DM, DM);

  for (int i = 0; i < 2; ++i) {
    ln_kernel<0><<<L, 64, 0, stream>>>(h, ln_w + i * DM, ln_b + i * DM,
                                       nullptr, hnh, hnl);
    // in_proj: xz(split) = hn @ W^T  N=2048,K=512 (unsplit)
    gemm_mfma<128, 2, 2, 0, 0, 0, 1><<<dim3(16, 32), 256, 0, stream>>>(
        hnh, hnl, wih + (size_t)i * 2 * DI * DM, wil + (size_t)i * 2 * DI * DM,
        nullptr, nullptr, nullptr, xzh, xzl, L, 2 * DI, DM);
    conv_silu<<<L * DI / 256, 256, 0, stream>>>(
        xzh, xzl, conv_w + (size_t)i * DI * 4, conv_b + (size_t)i * DI,
        xch, xcl);
    // x_proj: dbc = xc @ W^T  N=64,K=1024 split 8; partial in xpart
    gemm_mfma<64, 4, 1, 0, 0, 0, 0, 1><<<dim3(1, 32, 8), 256, 0, stream>>>(
        xch, xcl, wxh + (size_t)i * 64 * DI, wxl + (size_t)i * 64 * DI,
        nullptr, nullptr, xpart, nullptr, nullptr, L, 64, DI);
    kreduce<8, 0, 0, 0><<<256, 256, 0, stream>>>(
        xpart, nullptr, nullptr, dbc, L * 64, 64);
    dt_fast<<<dim3(DI / 256, L / 32), 256, 0, stream>>>(
        dbc, dt_w + (size_t)i * DI * RNK, dt_b + (size_t)i * DI, dt);
    if (big) {
      scan_part1<32><<<dim3(DI / BD, 128), 256, 0, stream>>>(
          xch, xcl, dt, dbc, A_log + (size_t)i * DI * DS, Pbuf, Sbuf);
      scan_carry<<<DI * DS / 256, 256, 0, stream>>>(Pbuf, Sbuf, nc);
      scan_part2<32><<<dim3(DI / BD, 128), 256, 0, stream>>>(
          xch, xcl, dt, dbc, Sbuf, xzh, xzl, yh, yl,
          A_log + (size_t)i * DI * DS, D_p + (size_t)i * DI);
    } else {
      scan_part1<64><<<dim3(DI / BD, 64), 256, 0, stream>>>(
          xch, xcl, dt, dbc, A_log + (size_t)i * DI * DS, Pbuf, Sbuf);
      scan_carry<<<DI * DS / 256, 256, 0, stream>>>(Pbuf, Sbuf, nc);
      scan_part2<64><<<dim3(DI / BD, 64), 256, 0, stream>>>(
          xch, xcl, dt, dbc, Sbuf, xzh, xzl, yh, yl,
          A_log + (size_t)i * DI * DS, D_p + (size_t)i * DI);
    }
    // out_proj: h += y @ W^T  N=512,K=1024 split 2; partial in gpart
    gemm_mfma<128, 2, 2, 0, 0, 0, 0, 1><<<dim3(4, 32, 2), 256, 0, stream>>>(
        yh, yl, woh + (size_t)i * DM * DI, wol + (size_t)i * DM * DI,
        nullptr, nullptr, gpart, nullptr, nullptr, L, DM, DI);
    kreduce<2, 0, 0, 1><<<2048, 256, 0, stream>>>(
        gpart, nullptr, h, h, L * DM, DM);
  }

  // final layernorm -> hn (f32) + hnh/hnl
  ln_kernel<1><<<L, 64, 0, stream>>>(h, norm_w, norm_b, hn, hnh, hnl);
  // attn1: tb = tanh(hn @ w1^T + b1)  N=128,K=512 split 4; partial in apart
  gemm_mfma<128, 2, 2, 0, 0, 0, 0, 1><<<dim3(1, 32, 4), 256, 0, stream>>>(
      hnh, hnl, wah, wal, nullptr, nullptr, apart, nullptr, nullptr,
      L, 128, DM);
  kreduce<4, 2, 1, 0><<<512, 256, 0, stream>>>(
      apart, attn_b1, nullptr, tb, L * 128, 128);
  attn2_kernel<<<L, 64, 0, stream>>>(tb, attn_w2, attn_b2, avec);
  softmax4096<<<1, 256, 0, stream>>>(avec, wvec);
  pooled_partial<<<32, 256, 0, stream>>>(wvec, hn, part);
  pooled_reduce<<<2, 256, 0, stream>>>(part, pool);
  logits_kernel<<<1, 128, 0, stream>>>(pool, cls_w, cls_b, (float*)d_out);
}

// Round 13
// 445.126 us; speedup vs baseline: 1.1395x; 1.1395x over previous
//
#include <hip/hip_runtime.h>
#include <math.h>

#define L 4096
#define DM 512
#define DI 1024
#define DS 16
#define RNK 32
#define NC 64   // scan chunks
#define CT 64   // timesteps per chunk
#define BD 64   // d-columns per scan block

typedef unsigned short u16;
typedef __attribute__((ext_vector_type(8))) short bfv8;   // 8 bf16 (4 VGPRs)
typedef __attribute__((ext_vector_type(4))) float f32x4;

__device__ __forceinline__ u16 f2bf(float f) {
  unsigned int u = __float_as_uint(f);
  u = (u + 0x7fff + ((u >> 16) & 1)) >> 16;   // round-to-nearest-even
  return (u16)u;
}
__device__ __forceinline__ float bf2f(u16 h) {
  return __uint_as_float(((unsigned int)h) << 16);
}

__device__ __forceinline__ void gload16(const void* g, void* l) {
  __builtin_amdgcn_global_load_lds(
      (const __attribute__((address_space(1))) void*)g,
      (__attribute__((address_space(3))) void*)l, 16, 0, 0);
}

// ---------------------------------------------------------------------------
// split fp32 -> (hi, lo) bf16 planes. n4 = n/4.
// ---------------------------------------------------------------------------
__global__ __launch_bounds__(256) void split_bf(
    const float* __restrict__ in, u16* __restrict__ hi, u16* __restrict__ lo,
    int n4) {
  int i = blockIdx.x * 256 + threadIdx.x;
  if (i >= n4) return;
  float4 v = ((const float4*)in)[i];
  ushort4 h4, l4;
  h4.x = f2bf(v.x); l4.x = f2bf(v.x - bf2f(h4.x));
  h4.y = f2bf(v.y); l4.y = f2bf(v.y - bf2f(h4.y));
  h4.z = f2bf(v.z); l4.z = f2bf(v.z - bf2f(h4.z));
  h4.w = f2bf(v.w); l4.w = f2bf(v.w - bf2f(h4.w));
  ((ushort4*)hi)[i] = h4;
  ((ushort4*)lo)[i] = l4;
}

// ---------------------------------------------------------------------------
// Split-bf16 MFMA GEMM:  C = A @ W^T.  BMT: row-tile (64 doubles the grid vs
// 128 -> fixes the 2-blocks/CU grid limit seen in R12). PARTIAL: grid.z
// K-slices write raw fp32 partials (epilogue deferred to kreduce).
// ---------------------------------------------------------------------------
template <int BMT, int BN_, int WM, int WN, int ACT, int BIAS, int RES,
          int OSPLIT, int PARTIAL = 0>
__global__ __launch_bounds__(256) void gemm_mfma(
    const u16* __restrict__ Ah, const u16* __restrict__ Al,
    const u16* __restrict__ Wh, const u16* __restrict__ Wl,
    const float* __restrict__ bias, const float* __restrict__ res,
    float* __restrict__ Cf, u16* __restrict__ Ch, u16* __restrict__ Cl,
    int M, int N, int K) {
  constexpr int BK_ = 32;
  constexpr int MSUB = BMT / WM, NSUB = BN_ / WN;
  constexpr int MR = MSUB / 16, NR = NSUB / 16;
  __shared__ u16 smem[2 * BMT * BK_ + 2 * BN_ * BK_];
  u16* sAh = smem;
  u16* sAl = smem + BMT * BK_;
  u16* sBh = smem + 2 * BMT * BK_;
  u16* sBl = sBh + BN_ * BK_;
  const int lane = threadIdx.x & 63, wid = threadIdx.x >> 6;
  const int wrow = wid / WN, wcol = wid % WN;
  const int bm = blockIdx.y * BMT, bn = blockIdx.x * BN_;
  const int fr = lane & 15, kq = lane >> 4;
  const int kz = blockIdx.z;
  const int kslice = K / gridDim.z;
  const int kbeg = kz * kslice, kend = kbeg + kslice;

  f32x4 acc[MR][NR];
#pragma unroll
  for (int m = 0; m < MR; ++m)
#pragma unroll
    for (int n = 0; n < NR; ++n) acc[m][n] = (f32x4){0.f, 0.f, 0.f, 0.f};

  for (int kt = kbeg; kt < kend; kt += BK_) {
#pragma unroll
    for (int s = wid; s < BMT / 16; s += 4) {
      int chunk = s * 64 + lane;
      int row = chunk >> 2, c4 = chunk & 3;
      size_t go = (size_t)(bm + row) * K + kt + c4 * 8;
      gload16(Ah + go, sAh + s * 512);
      gload16(Al + go, sAl + s * 512);
    }
#pragma unroll
    for (int s = wid; s < BN_ / 16; s += 4) {
      int chunk = s * 64 + lane;
      int row = chunk >> 2, c4 = chunk & 3;
      size_t go = (size_t)(bn + row) * K + kt + c4 * 8;
      gload16(Wh + go, sBh + s * 512);
      gload16(Wl + go, sBl + s * 512);
    }
    __syncthreads();

    bfv8 ah[MR], al[MR], bh[NR], bl[NR];
#pragma unroll
    for (int m = 0; m < MR; ++m) {
      int row = wrow * MSUB + m * 16 + fr;
      ah[m] = *(const bfv8*)(sAh + row * 32 + kq * 8);
      al[m] = *(const bfv8*)(sAl + row * 32 + kq * 8);
    }
#pragma unroll
    for (int n = 0; n < NR; ++n) {
      int row = wcol * NSUB + n * 16 + fr;
      bh[n] = *(const bfv8*)(sBh + row * 32 + kq * 8);
      bl[n] = *(const bfv8*)(sBl + row * 32 + kq * 8);
    }
#pragma unroll
    for (int m = 0; m < MR; ++m)
#pragma unroll
      for (int n = 0; n < NR; ++n) {
        acc[m][n] = __builtin_amdgcn_mfma_f32_16x16x32_bf16(ah[m], bh[n], acc[m][n], 0, 0, 0);
        acc[m][n] = __builtin_amdgcn_mfma_f32_16x16x32_bf16(ah[m], bl[n], acc[m][n], 0, 0, 0);
        acc[m][n] = __builtin_amdgcn_mfma_f32_16x16x32_bf16(al[m], bh[n], acc[m][n], 0, 0, 0);
      }
    __syncthreads();
  }

#pragma unroll
  for (int m = 0; m < MR; ++m)
#pragma unroll
    for (int n = 0; n < NR; ++n) {
      int col = bn + wcol * NSUB + n * 16 + fr;
      float bv = 0.f;
      if (BIAS) bv = bias[col];
#pragma unroll
      for (int j = 0; j < 4; ++j) {
        int row = bm + wrow * MSUB + m * 16 + kq * 4 + j;
        if (PARTIAL) {
          Cf[(size_t)kz * M * N + (size_t)row * N + col] = acc[m][n][j];
          continue;
        }
        float v = acc[m][n][j] + bv;
        if (ACT == 1) v = fmaxf(v, 0.f);
        if (ACT == 2) v = tanhf(v);
        if (RES) v += res[(size_t)row * N + col];
        if (OSPLIT) {
          u16 hv = f2bf(v);
          Ch[(size_t)row * N + col] = hv;
          Cl[(size_t)row * N + col] = f2bf(v - bf2f(hv));
        } else {
          Cf[(size_t)row * N + col] = v;
        }
      }
    }
}

// ---------------------------------------------------------------------------
// kreduce: sum KS fp32 partials + epilogue. i indexes float4; N % 4 == 0.
// ---------------------------------------------------------------------------
template <int KS, int ACT, int BIAS, int RES>
__global__ __launch_bounds__(256) void kreduce(
    const float* __restrict__ part, const float* __restrict__ bias,
    const float* __restrict__ res, float* __restrict__ Cf, int MN, int N) {
  int i = blockIdx.x * 256 + threadIdx.x;
  if (i * 4 >= MN) return;
  const float4* p4 = (const float4*)part;
  float4 s = p4[i];
#pragma unroll
  for (int k = 1; k < KS; ++k) {
    float4 v = p4[i + (size_t)k * (MN / 4)];
    s.x += v.x; s.y += v.y; s.z += v.z; s.w += v.w;
  }
  if (BIAS) {
    int col = (i * 4) % N;
    float4 b = *(const float4*)(bias + col);
    s.x += b.x; s.y += b.y; s.z += b.z; s.w += b.w;
  }
  if (ACT == 1) {
    s.x = fmaxf(s.x, 0.f); s.y = fmaxf(s.y, 0.f);
    s.z = fmaxf(s.z, 0.f); s.w = fmaxf(s.w, 0.f);
  }
  if (ACT == 2) {
    s.x = tanhf(s.x); s.y = tanhf(s.y); s.z = tanhf(s.z); s.w = tanhf(s.w);
  }
  if (RES) {
    float4 r = ((const float4*)res)[i];
    s.x += r.x; s.y += r.y; s.z += r.z; s.w += r.w;
  }
  ((float4*)Cf)[i] = s;
}

// ---------------------------------------------------------------------------
// LayerNorm rows of (L,512); writes bf16 hi/lo planes (+fp32 if F32OUT).
// ---------------------------------------------------------------------------
template <int F32OUT>
__global__ __launch_bounds__(64) void ln_kernel(
    const float* __restrict__ x, const float* __restrict__ w,
    const float* __restrict__ b, float* __restrict__ of,
    u16* __restrict__ oh, u16* __restrict__ ol) {
  const int l = blockIdx.x, t = threadIdx.x;
  const float* row = x + (size_t)l * DM;
  float4 v0 = *(const float4*)(row + t * 8);
  float4 v1 = *(const float4*)(row + t * 8 + 4);
  float vals[8] = {v0.x, v0.y, v0.z, v0.w, v1.x, v1.y, v1.z, v1.w};
  float s = 0.f;
#pragma unroll
  for (int i = 0; i < 8; ++i) s += vals[i];
#pragma unroll
  for (int off = 1; off < 64; off <<= 1) s += __shfl_xor(s, off);
  float m = s * (1.f / DM);
  float q = 0.f;
#pragma unroll
  for (int i = 0; i < 8; ++i) { float dd = vals[i] - m; q += dd * dd; }
#pragma unroll
  for (int off = 1; off < 64; off <<= 1) q += __shfl_xor(q, off);
  float rs = 1.f / sqrtf(q * (1.f / DM) + 1e-5f);
  float4 w0 = *(const float4*)(w + t * 8);
  float4 w1 = *(const float4*)(w + t * 8 + 4);
  float4 b0 = *(const float4*)(b + t * 8);
  float4 b1 = *(const float4*)(b + t * 8 + 4);
  float wv[8] = {w0.x, w0.y, w0.z, w0.w, w1.x, w1.y, w1.z, w1.w};
  float bb[8] = {b0.x, b0.y, b0.z, b0.w, b1.x, b1.y, b1.z, b1.w};
  ushort4 h4[2], l4[2];
#pragma unroll
  for (int i = 0; i < 8; ++i) {
    float o = (vals[i] - m) * rs * wv[i] + bb[i];
    u16 hv = f2bf(o);
    ((u16*)h4)[i] = hv;
    ((u16*)l4)[i] = f2bf(o - bf2f(hv));
    vals[i] = o;
  }
  size_t base = (size_t)l * DM + t * 8;
  *(ushort4*)(oh + base) = h4[0];
  *(ushort4*)(oh + base + 4) = h4[1];
  *(ushort4*)(ol + base) = l4[0];
  *(ushort4*)(ol + base + 4) = l4[1];
  if (F32OUT) {
    *(float4*)(of + base) = make_float4(vals[0], vals[1], vals[2], vals[3]);
    *(float4*)(of + base + 4) = make_float4(vals[4], vals[5], vals[6], vals[7]);
  }
}

// ---------------------------------------------------------------------------
// Depthwise causal conv (k=4) + SiLU; in/out are bf16 hi/lo planes.
// ---------------------------------------------------------------------------
__global__ __launch_bounds__(256) void conv_silu(
    const u16* __restrict__ xzh, const u16* __restrict__ xzl,
    const float* __restrict__ cw, const float* __restrict__ cb,
    u16* __restrict__ xch, u16* __restrict__ xcl) {
  const int idx = blockIdx.x * 256 + threadIdx.x;
  const int l = idx >> 10, d = idx & 1023;
  float s = cb[d];
  float4 w4 = *(const float4*)(cw + d * 4);
  const float wk[4] = {w4.x, w4.y, w4.z, w4.w};
#pragma unroll
  for (int k = 0; k < 4; ++k) {
    int ll = l - 3 + k;
    if (ll >= 0) {
      size_t o = (size_t)ll * (2 * DI) + d;
      s += (bf2f(xzh[o]) + bf2f(xzl[o])) * wk[k];
    }
  }
  float v = s / (1.f + __expf(-s));
  u16 hv = f2bf(v);
  xch[idx] = hv;
  xcl[idx] = f2bf(v - bf2f(hv));
}

// ---------------------------------------------------------------------------
// dt = softplus(dbc[:, :32] @ dtw^T + dtb), tiled: block = 256 d x 32 l.
// ---------------------------------------------------------------------------
__global__ __launch_bounds__(256) void dt_fast(
    const float* __restrict__ dbc, const float* __restrict__ dtw,
    const float* __restrict__ dtb, float* __restrict__ dt) {
  __shared__ float s[32][33];
  const int t = threadIdx.x;
  const int d = blockIdx.x * 256 + t;
  const int l0 = blockIdx.y * 32;
  {
    int r = t >> 3, c4 = t & 7;
    float4 v = *(const float4*)(dbc + (size_t)(l0 + r) * 64 + c4 * 4);
    s[r][c4 * 4 + 0] = v.x; s[r][c4 * 4 + 1] = v.y;
    s[r][c4 * 4 + 2] = v.z; s[r][c4 * 4 + 3] = v.w;
  }
  __syncthreads();
  float wk[RNK];
#pragma unroll
  for (int k = 0; k < RNK; k += 4) {
    float4 w4 = *(const float4*)(dtw + (size_t)d * RNK + k);
    wk[k] = w4.x; wk[k + 1] = w4.y; wk[k + 2] = w4.z; wk[k + 3] = w4.w;
  }
  const float bias = dtb[d];
  for (int l = 0; l < 32; ++l) {
    float acc = bias;
#pragma unroll
    for (int k = 0; k < RNK; ++k) acc += s[l][k] * wk[k];
    float sp = fmaxf(acc, 0.f) + __logf(1.f + __expf(-fabsf(acc)));
    dt[(size_t)(l0 + l) * DI + d] = sp;
  }
}

// ---------------------------------------------------------------------------
// LDS-staged chunked scan (proven R11 config: NC=64, CT=64).
// Block: 64 d x 64 timesteps, 256 thr (4 subs/d, 4 states/sub).
// part1 uses P = exp(A * sum(dt)).
// ---------------------------------------------------------------------------
__global__ __launch_bounds__(256) void scan_part1(
    const u16* __restrict__ xch, const u16* __restrict__ xcl,
    const float* __restrict__ dt, const float* __restrict__ dbc,
    const float* __restrict__ A_log, float* __restrict__ Pbuf,
    float* __restrict__ Sbuf) {
  __shared__ float sdt[CT * BD];
  __shared__ float sx[CT * BD];
  __shared__ float sB[CT * 16];
  const int t = threadIdx.x;
  const int d0 = blockIdx.x * BD;
  const int c = blockIdx.y;
  const int l0 = c * CT;
#pragma unroll
  for (int it = 0; it < 16; ++it) {
    int idx = it * 256 + t;
    int l = idx >> 6, dc = idx & 63;
    size_t o = (size_t)(l0 + l) * DI + d0 + dc;
    sdt[idx] = dt[o];
    sx[idx] = bf2f(xch[o]) + bf2f(xcl[o]);
  }
#pragma unroll
  for (int it = 0; it < 4; ++it) {
    int idx = it * 256 + t;
    int l = idx >> 4, col = idx & 15;
    sB[idx] = dbc[(size_t)(l0 + l) * 64 + RNK + col];
  }
  __syncthreads();
  const int sub = t & 3;
  const int dl = t >> 2;
  const int d = d0 + dl;
  float A[4];
  {
    float4 a4 = *(const float4*)(A_log + (size_t)d * DS + sub * 4);
    A[0] = -__expf(a4.x); A[1] = -__expf(a4.y);
    A[2] = -__expf(a4.z); A[3] = -__expf(a4.w);
  }
  float S4[4] = {0.f, 0.f, 0.f, 0.f};
  float dtsum = 0.f;
  for (int l = 0; l < CT; ++l) {
    float dtv = sdt[l * BD + dl];
    float xv = sx[l * BD + dl];
    float4 Bv = *(const float4*)(sB + l * 16 + sub * 4);
    float dx = dtv * xv;
    dtsum += dtv;
    const float B[4] = {Bv.x, Bv.y, Bv.z, Bv.w};
#pragma unroll
    for (int j = 0; j < 4; ++j) {
      float dA = __expf(dtv * A[j]);
      S4[j] = dA * S4[j] + B[j] * dx;
    }
  }
  size_t po = ((size_t)c * DI + d) * DS + sub * 4;
  *(float4*)(Pbuf + po) = make_float4(__expf(A[0] * dtsum), __expf(A[1] * dtsum),
                                      __expf(A[2] * dtsum), __expf(A[3] * dtsum));
  *(float4*)(Sbuf + po) = make_float4(S4[0], S4[1], S4[2], S4[3]);
}

// carry: sequential over chunks; overwrites S in place with Hin (pre-state).
__global__ __launch_bounds__(256) void scan_carry(
    const float* __restrict__ Pbuf, float* __restrict__ Sbuf) {
  const int p = blockIdx.x * 256 + threadIdx.x;  // 16384
  float H = 0.f;
  for (int c = 0; c < NC; ++c) {
    const size_t o = (size_t)c * (DI * DS) + p;
    float Pv = Pbuf[o], Sv = Sbuf[o];
    Sbuf[o] = H;
    H = Pv * H + Sv;
  }
}

__global__ __launch_bounds__(256) void scan_part2(
    const u16* __restrict__ xch, const u16* __restrict__ xcl,
    const float* __restrict__ dt, const float* __restrict__ dbc,
    const float* __restrict__ Hin, const u16* __restrict__ xzh,
    const u16* __restrict__ xzl, u16* __restrict__ yh, u16* __restrict__ yl,
    const float* __restrict__ A_log, const float* __restrict__ D_p) {
  __shared__ float sdt[CT * BD];
  __shared__ float sx[CT * BD];
  __shared__ float sB[CT * 16];
  __shared__ float sC[CT * 16];
  const int t = threadIdx.x;
  const int d0 = blockIdx.x * BD;
  const int c = blockIdx.y;
  const int l0 = c * CT;
#pragma unroll
  for (int it = 0; it < 16; ++it) {
    int idx = it * 256 + t;
    int l = idx >> 6, dc = idx & 63;
    size_t o = (size_t)(l0 + l) * DI + d0 + dc;
    sdt[idx] = dt[o];
    sx[idx] = bf2f(xch[o]) + bf2f(xcl[o]);
  }
#pragma unroll
  for (int it = 0; it < 4; ++it) {
    int idx = it * 256 + t;
    int l = idx >> 4, col = idx & 15;
    size_t ro = (size_t)(l0 + l) * 64 + RNK + col;
    sB[idx] = dbc[ro];
    sC[idx] = dbc[ro + DS];
  }
  __syncthreads();
  const int sub = t & 3;
  const int dl = t >> 2;
  const int d = d0 + dl;
  float A[4], hst[4];
  {
    float4 a4 = *(const float4*)(A_log + (size_t)d * DS + sub * 4);
    A[0] = -__expf(a4.x); A[1] = -__expf(a4.y);
    A[2] = -__expf(a4.z); A[3] = -__expf(a4.w);
    float4 h4 = *(const float4*)(Hin + ((size_t)c * DI + d) * DS + sub * 4);
    hst[0] = h4.x; hst[1] = h4.y; hst[2] = h4.z; hst[3] = h4.w;
  }
  const float Dp = D_p[d];
  for (int l = 0; l < CT; ++l) {
    float dtv = sdt[l * BD + dl];
    float xv = sx[l * BD + dl];
    float4 Bv = *(const float4*)(sB + l * 16 + sub * 4);
    float4 Cv = *(const float4*)(sC + l * 16 + sub * 4);
    float dx = dtv * xv;
    const float B[4] = {Bv.x, Bv.y, Bv.z, Bv.w};
    const float C[4] = {Cv.x, Cv.y, Cv.z, Cv.w};
    float y = 0.f;
#pragma unroll
    for (int j = 0; j < 4; ++j) {
      float dA = __expf(dtv * A[j]);
      hst[j] = dA * hst[j] + B[j] * dx;
      y += hst[j] * C[j];
    }
    y += __shfl_xor(y, 1);
    y += __shfl_xor(y, 2);
    if (sub == 0) {
      size_t o = (size_t)(l0 + l) * DI + d;
      size_t zo = (size_t)(l0 + l) * (2 * DI) + DI + d;
      float zv = bf2f(xzh[zo]) + bf2f(xzl[zo]);
      float yv = y + Dp * xv;
      float out = yv * (zv / (1.f + __expf(-zv)));
      u16 hv = f2bf(out);
      yh[o] = hv;
      yl[o] = f2bf(out - bf2f(hv));
    }
  }
}

// ---------------------------------------------------------------------------
// tail: attention pooling + logits
// ---------------------------------------------------------------------------
__global__ __launch_bounds__(64) void attn2_kernel(
    const float* __restrict__ tb, const float* __restrict__ w2,
    const float* __restrict__ b2, float* __restrict__ avec) {
  const int l = blockIdx.x, t = threadIdx.x;
  float acc = tb[(size_t)l * 128 + t] * w2[t] +
              tb[(size_t)l * 128 + 64 + t] * w2[64 + t];
#pragma unroll
  for (int off = 1; off < 64; off <<= 1) acc += __shfl_xor(acc, off);
  if (t == 0) avec[l] = acc + b2[0];
}

__global__ __launch_bounds__(256) void softmax4096(
    const float* __restrict__ a, float* __restrict__ w) {
  __shared__ float sm[4];
  const int t = threadIdx.x;
  float vals[16];
  float m = -1e30f;
#pragma unroll
  for (int i = 0; i < 16; ++i) { vals[i] = a[t + i * 256]; m = fmaxf(m, vals[i]); }
#pragma unroll
  for (int off = 1; off < 64; off <<= 1) m = fmaxf(m, __shfl_xor(m, off));
  if ((t & 63) == 0) sm[t >> 6] = m;
  __syncthreads();
  m = fmaxf(fmaxf(sm[0], sm[1]), fmaxf(sm[2], sm[3]));
  __syncthreads();
  float s = 0.f;
#pragma unroll
  for (int i = 0; i < 16; ++i) { vals[i] = expf(vals[i] - m); s += vals[i]; }
#pragma unroll
  for (int off = 1; off < 64; off <<= 1) s += __shfl_xor(s, off);
  if ((t & 63) == 0) sm[t >> 6] = s;
  __syncthreads();
  s = sm[0] + sm[1] + sm[2] + sm[3];
  float inv = 1.f / s;
#pragma unroll
  for (int i = 0; i < 16; ++i) w[t + i * 256] = vals[i] * inv;
}

__global__ __launch_bounds__(256) void pooled_partial(
    const float* __restrict__ w, const float* __restrict__ hn,
    float* __restrict__ partial) {
  const int b = blockIdx.x;
  const int t = threadIdx.x;
  float acc0 = 0.f, acc1 = 0.f;
  for (int l = b * 128; l < b * 128 + 128; ++l) {
    float wl = w[l];
    acc0 += wl * hn[(size_t)l * DM + t];
    acc1 += wl * hn[(size_t)l * DM + t + 256];
  }
  partial[b * DM + t] = acc0;
  partial[b * DM + t + 256] = acc1;
}

__global__ __launch_bounds__(256) void pooled_reduce(
    const float* __restrict__ partial, float* __restrict__ pooled) {
  const int d = blockIdx.x * 256 + threadIdx.x;
  float s = 0.f;
  for (int b = 0; b < 32; ++b) s += partial[b * DM + d];
  pooled[d] = s;
}

__global__ __launch_bounds__(128) void logits_kernel(
    const float* __restrict__ pooled, const float* __restrict__ cls_w,
    const float* __restrict__ cls_b, float* __restrict__ out) {
  const int c = threadIdx.x >> 6, lane = threadIdx.x & 63;
  float acc = 0.f;
  for (int j = lane; j < DM; j += 64) acc += pooled[j] * cls_w[c * DM + j];
#pragma unroll
  for (int off = 1; off < 64; off <<= 1) acc += __shfl_xor(acc, off);
  if (lane == 0) out[c] = acc + cls_b[c];
}

// ---------------------------------------------------------------------------
extern "C" void kernel_launch(void* const* d_in, const int* in_sizes, int n_in,
                              void* d_out, int out_size, void* d_ws,
                              size_t ws_size, hipStream_t stream) {
  const float* x        = (const float*)d_in[0];
  const float* fc1_w    = (const float*)d_in[1];
  const float* fc1_b    = (const float*)d_in[2];
  const float* ln_w     = (const float*)d_in[3];
  const float* ln_b     = (const float*)d_in[4];
  const float* in_projw = (const float*)d_in[5];
  const float* conv_w   = (const float*)d_in[6];
  const float* conv_b   = (const float*)d_in[7];
  const float* x_projw  = (const float*)d_in[8];
  const float* dt_w     = (const float*)d_in[9];
  const float* dt_b     = (const float*)d_in[10];
  const float* A_log    = (const float*)d_in[11];
  const float* D_p      = (const float*)d_in[12];
  const float* out_projw= (const float*)d_in[13];
  const float* norm_w   = (const float*)d_in[14];
  const float* norm_b   = (const float*)d_in[15];
  const float* attn_w1  = (const float*)d_in[16];
  const float* attn_b1  = (const float*)d_in[17];
  const float* attn_w2  = (const float*)d_in[18];
  const float* attn_b2  = (const float*)d_in[19];
  const float* cls_w    = (const float*)d_in[20];
  const float* cls_b    = (const float*)d_in[21];

  char* p = (char*)d_ws;
  const size_t MB = 1024 * 1024;
  float* h    = (float*)(p);             // 8MB: L*DM f32
  float* dbc  = (float*)(p + 8 * MB);    // 1MB: L*64 f32
  float* dt   = (float*)(p + 9 * MB);    // 16MB: L*DI f32
  float* tb   = dt;                      // attn1 out aliases dt
  float* gpart= dt;                      // fc1/out_proj K-split partials (16MB)
  float* Pbuf = (float*)(p + 25 * MB);   // 4MB
  float* Sbuf = (float*)(p + 29 * MB);   // 4MB (Hin in-place)
  float* xpart= Pbuf;                    // x_proj partials (8MB, pre-scan)
  float* hn   = Pbuf;                    // f32, used only after scans done
  float* avec = (float*)(p + 33 * MB);           // 16KB
  float* wvec = avec + L;                        // 16KB
  float* part = wvec + L;                        // 64KB
  float* pool = part + 32 * DM;                  // 2KB
  u16* xzh = (u16*)(p + 34 * MB);        // 16MB: L*2DI
  u16* xzl = (u16*)(p + 50 * MB);        // 16MB
  float* apart = (float*)(p + 34 * MB);  // attn1 partials (8MB, xz dead then)
  u16* yh  = (u16*)(p + 66 * MB);        // 8MB: L*DI (hnh aliases)
  u16* yl  = (u16*)(p + 74 * MB);        // 8MB (hnl aliases)
  u16* hnh = yh;
  u16* hnl = yl;
  u16* xch = (u16*)(p + 82 * MB);        // 8MB: L*DI (xh aliases)
  u16* xcl = (u16*)(p + 90 * MB);        // 8MB (xl aliases)
  u16* xh = xch;
  u16* xl = xcl;
  u16* wfh = (u16*)(p + 98 * MB);        // 1MB: fc1_w 512*1024
  u16* wfl = wfh + 524288;               // 1MB
  u16* wih = (u16*)(p + 100 * MB);       // 4MB: in_proj 2*2048*512
  u16* wil = (u16*)(p + 104 * MB);       // 4MB
  u16* wxh = (u16*)(p + 108 * MB);       // .25MB: x_proj 2*64*1024
  u16* wxl = wxh + 131072;
  u16* woh = (u16*)(p + 109 * MB);       // 2MB: out_proj 2*512*1024
  u16* wol = (u16*)(p + 111 * MB);       // 2MB
  u16* wah = (u16*)(p + 113 * MB);       // .125MB: attn_w1 128*512
  u16* wal = wah + 65536;

  // ---- split inputs/weights to bf16 hi/lo planes ----
  split_bf<<<4096, 256, 0, stream>>>(x, xh, xl, L * DI / 4);
  split_bf<<<512, 256, 0, stream>>>(fc1_w, wfh, wfl, 524288 / 4);
  split_bf<<<2048, 256, 0, stream>>>(in_projw, wih, wil, 2097152 / 4);
  split_bf<<<128, 256, 0, stream>>>(x_projw, wxh, wxl, 131072 / 4);
  split_bf<<<1024, 256, 0, stream>>>(out_projw, woh, wol, 1048576 / 4);
  split_bf<<<64, 256, 0, stream>>>(attn_w1, wah, wal, 65536 / 4);

  // fc1: h = relu(x @ fc1_w^T + b)  K=1024 split 2; BM=64 -> 512 blocks
  gemm_mfma<64, 128, 2, 2, 0, 0, 0, 0, 1><<<dim3(4, 64, 2), 256, 0, stream>>>(
      xh, xl, wfh, wfl, nullptr, nullptr, gpart, nullptr, nullptr,
      L, DM, 1024);
  kreduce<2, 1, 1, 0><<<2048, 256, 0, stream>>>(
      gpart, fc1_b, nullptr, h, L * DM, DM);

  for (int i = 0; i < 2; ++i) {
    ln_kernel<0><<<L, 64, 0, stream>>>(h, ln_w + i * DM, ln_b + i * DM,
                                       nullptr, hnh, hnl);
    // in_proj: xz(split) = hn @ W^T  N=2048,K=512; BM=64 -> 1024 blocks
    gemm_mfma<64, 128, 2, 2, 0, 0, 0, 1><<<dim3(16, 64), 256, 0, stream>>>(
        hnh, hnl, wih + (size_t)i * 2 * DI * DM, wil + (size_t)i * 2 * DI * DM,
        nullptr, nullptr, nullptr, xzh, xzl, L, 2 * DI, DM);
    conv_silu<<<L * DI / 256, 256, 0, stream>>>(
        xzh, xzl, conv_w + (size_t)i * DI * 4, conv_b + (size_t)i * DI,
        xch, xcl);
    // x_proj: dbc = xc @ W^T  N=64,K=1024 split 8; BM=64 -> 512 blocks
    gemm_mfma<64, 64, 2, 2, 0, 0, 0, 0, 1><<<dim3(1, 64, 8), 256, 0, stream>>>(
        xch, xcl, wxh + (size_t)i * 64 * DI, wxl + (size_t)i * 64 * DI,
        nullptr, nullptr, xpart, nullptr, nullptr, L, 64, DI);
    kreduce<8, 0, 0, 0><<<256, 256, 0, stream>>>(
        xpart, nullptr, nullptr, dbc, L * 64, 64);
    dt_fast<<<dim3(DI / 256, L / 32), 256, 0, stream>>>(
        dbc, dt_w + (size_t)i * DI * RNK, dt_b + (size_t)i * DI, dt);
    scan_part1<<<dim3(DI / BD, NC), 256, 0, stream>>>(
        xch, xcl, dt, dbc, A_log + (size_t)i * DI * DS, Pbuf, Sbuf);
    scan_carry<<<DI * DS / 256, 256, 0, stream>>>(Pbuf, Sbuf);
    scan_part2<<<dim3(DI / BD, NC), 256, 0, stream>>>(
        xch, xcl, dt, dbc, Sbuf, xzh, xzl, yh, yl,
        A_log + (size_t)i * DI * DS, D_p + (size_t)i * DI);
    // out_proj: h += y @ W^T  N=512,K=1024 split 2; BM=64 -> 512 blocks
    gemm_mfma<64, 128, 2, 2, 0, 0, 0, 0, 1><<<dim3(4, 64, 2), 256, 0, stream>>>(
        yh, yl, woh + (size_t)i * DM * DI, wol + (size_t)i * DM * DI,
        nullptr, nullptr, gpart, nullptr, nullptr, L, DM, DI);
    kreduce<2, 0, 0, 1><<<2048, 256, 0, stream>>>(
        gpart, nullptr, h, h, L * DM, DM);
  }

  // final layernorm -> hn (f32) + hnh/hnl
  ln_kernel<1><<<L, 64, 0, stream>>>(h, norm_w, norm_b, hn, hnh, hnl);
  // attn1: tb = tanh(hn @ w1^T + b1)  N=128,K=512 split 4; BM=64 -> 256 blks
  gemm_mfma<64, 128, 2, 2, 0, 0, 0, 0, 1><<<dim3(1, 64, 4), 256, 0, stream>>>(
      hnh, hnl, wah, wal, nullptr, nullptr, apart, nullptr, nullptr,
      L, 128, DM);
  kreduce<4, 2, 1, 0><<<512, 256, 0, stream>>>(
      apart, attn_b1, nullptr, tb, L * 128, 128);
  attn2_kernel<<<L, 64, 0, stream>>>(tb, attn_w2, attn_b2, avec);
  softmax4096<<<1, 256, 0, stream>>>(avec, wvec);
  pooled_partial<<<32, 256, 0, stream>>>(wvec, hn, part);
  pooled_reduce<<<2, 256, 0, stream>>>(part, pool);
  logits_kernel<<<1, 128, 0, stream>>>(pool, cls_w, cls_b, (float*)d_out);
}